// Round 8
// baseline (700.096 us; speedup 1.0000x reference)
//
#include <hip/hip_runtime.h>

using s8 = __attribute__((ext_vector_type(8))) short;
using f4 = __attribute__((ext_vector_type(4))) float;

constexpr int WIDTH   = 16;
constexpr int HID     = 512;
constexpr int NHEADS  = 8;
constexpr int DK      = 64;
constexpr int NLAYERS = 2;
constexpr int NHW     = 2;
constexpr int B       = 4;
constexpr int S       = 1024;
constexpr int PAD     = S + 2 * WIDTH;   // 1056
constexpr int RS      = 1024;            // split row stride (shorts): [H(512)|L(512)]

// Split-bf16: x = h + l. GEMM reads A as [H,L,H], B as [H,H,L] over virtual
// K2=1536 -> Ah*Bh + Al*Bh + Ah*Bl (drops only Al*Bl ~ 2^-18).
__device__ inline unsigned short f2bf(float x) {
    union { float f; unsigned u; } c; c.f = x;
    unsigned r = c.u + 0x7fffu + ((c.u >> 16) & 1u);
    return (unsigned short)(r >> 16);
}
__device__ inline float bf2f(unsigned short h) {
    union { float f; unsigned u; } c; c.u = ((unsigned)h) << 16; return c.f;
}
__device__ inline void split2(float x, unsigned short& h, unsigned short& l) {
    h = f2bf(x);
    l = f2bf(x - bf2f(h));
}
__device__ inline void store_split4(unsigned short* dst, float4 v) {
    unsigned short h[4], l[4];
    split2(v.x, h[0], l[0]); split2(v.y, h[1], l[1]);
    split2(v.z, h[2], l[2]); split2(v.w, h[3], l[3]);
    uint2 hp, lp;
    hp.x = h[0] | ((unsigned)h[1] << 16); hp.y = h[2] | ((unsigned)h[3] << 16);
    lp.x = l[0] | ((unsigned)l[1] << 16); lp.y = l[2] | ((unsigned)l[3] << 16);
    *(uint2*)(dst)       = hp;
    *(uint2*)(dst + 512) = lp;
}

// ---------------------------------------------------------------------------
__global__ __launch_bounds__(256) void build_pad_split(
    const float* __restrict__ src0, const float* __restrict__ src1,
    const float* __restrict__ front, const float* __restrict__ back,
    unsigned short* __restrict__ d0, unsigned short* __restrict__ d1)
{
    const float* x = blockIdx.z ? src1 : src0;
    unsigned short* xp2 = blockIdx.z ? d1 : d0;
    int idx = blockIdx.x * 256 + threadIdx.x;   // over B*PAD*128
    int c4 = idx & 127;
    int rest = idx >> 7;
    int p = rest % PAD;
    int b = rest / PAD;
    float4 val;
    if (p < WIDTH) {
        val = *(const float4*)(front + (size_t)p * HID + c4 * 4);
    } else if (p < WIDTH + S) {
        val = *(const float4*)(x + ((size_t)b * S + (p - WIDTH)) * HID + c4 * 4);
    } else {
        val = *(const float4*)(back + (size_t)(p - WIDTH - S) * HID + c4 * 4);
    }
    store_split4(xp2 + (size_t)(b * PAD + p) * RS + c4 * 4, val);
}

// ---------------------------------------------------------------------------
// per-use weight conversion (fallback paths): fp32 [R,HID] -> split [R,RS]
// ---------------------------------------------------------------------------
__global__ __launch_bounds__(256) void conv_w(
    const float* __restrict__ s0, const float* __restrict__ s1,
    unsigned short* __restrict__ w0, unsigned short* __restrict__ w1)
{
    const float* src = blockIdx.z ? s1 : s0;
    unsigned short* dst = blockIdx.z ? w1 : w0;
    int idx = blockIdx.x * 256 + threadIdx.x;
    int c4 = idx & 127;
    int r  = idx >> 7;
    float4 v = *(const float4*)(src + (size_t)r * HID + c4 * 4);
    store_split4(dst + (size_t)r * RS + c4 * 4, v);
}

// ---------------------------------------------------------------------------
// one-shot conversion of ALL weights -> w2all [2 dirs][8192 rows][RS]
// per (dir,layer): rows 0..2047 = lin_w (q,k,v,out stacked), 2048..4095 = hw_w
// ---------------------------------------------------------------------------
__global__ __launch_bounds__(256) void conv_all(
    const float* __restrict__ fw_lin_w, const float* __restrict__ bw_lin_w,
    const float* __restrict__ fw_hw_w,  const float* __restrict__ bw_hw_w,
    unsigned short* __restrict__ w2all)
{
    int idx = blockIdx.x * 256 + threadIdx.x;   // over 8192*128
    int c4 = idx & 127;
    int r  = idx >> 7;          // 0..8191
    int l  = r >> 12;           // layer
    int rr = r & 4095;
    const float* lin = blockIdx.z ? bw_lin_w : fw_lin_w;
    const float* hw  = blockIdx.z ? bw_hw_w  : fw_hw_w;
    const float* src = (rr < 2048)
        ? lin + ((size_t)l * 2048 + rr) * HID
        : hw  + ((size_t)l * 2048 + (rr - 2048)) * HID;
    float4 v = *(const float4*)(src + c4 * 4);
    store_split4(w2all + ((size_t)blockIdx.z * 8192 + r) * RS + c4 * 4, v);
}

// ---------------------------------------------------------------------------
// Split-bf16 MFMA GEMM (NT), DOUBLE-BUFFERED LDS, one barrier per K-iter.
// Prefetch for iter k+1 is issued right after the barrier (which drains the
// prefetch for iter k), so loads fly behind the 16-MFMA phase instead of
// being drained cold (R7: exposed latency, MfmaUtil 20%).
// LDS staging keeps R7's permuted-slot swizzle: coalesced fill (4 lanes per
// 64B line) + conflict-free fragment ds_read_b128 (2-way only).
// ---------------------------------------------------------------------------
__global__ __launch_bounds__(256) void gemm_split(
    const unsigned short* __restrict__ A0, const unsigned short* __restrict__ B0,
    const float* __restrict__ bias0, float* __restrict__ C0,
    const unsigned short* __restrict__ A1, const unsigned short* __restrict__ B1,
    const float* __restrict__ bias1, float* __restrict__ C1,
    int N)
{
    const unsigned short* A  = blockIdx.z ? A1 : A0;
    const unsigned short* Bw = blockIdx.z ? B1 : B0;
    const float* bias        = blockIdx.z ? bias1 : bias0;
    float* C                 = blockIdx.z ? C1 : C0;

    __shared__ unsigned short Als[2][128 * 32];
    __shared__ unsigned short Bls[2][128 * 32];

    const int tid  = threadIdx.x;
    const int wave = tid >> 6;
    const int lane = tid & 63;
    const int bm = blockIdx.y * 128;
    const int bn = blockIdx.x * 128;
    const int wm = (wave >> 1) * 64;
    const int wn = (wave & 1) * 64;

    const int c0 = wave * 2, c1 = wave * 2 + 1;
    const int lr = lane >> 2;                      // row within 16-row chunk
    const int kg = ((lane & 3) + (lr >> 1)) & 3;   // permuted k-granule
    const int sr0 = c0 * 16 + lr;
    const int sr1 = c1 * 16 + lr;
    const int sc  = kg * 8;
    const unsigned short* Ag0 = A  + (size_t)(bm + sr0) * RS + sc;
    const unsigned short* Ag1 = A  + (size_t)(bm + sr1) * RS + sc;
    const unsigned short* Bg0 = Bw + (size_t)(bn + sr0) * RS + sc;
    const unsigned short* Bg1 = Bw + (size_t)(bn + sr1) * RS + sc;
    const int ls0 = c0 * 512;
    const int ls1 = c1 * 512;

    const int fr = lane & 15;
    const int q  = lane >> 4;
    const int rslot = (4 * fr + ((q - (fr >> 1)) & 3)) * 8;

    auto prefetch = [&](int buf, int k0) {
        const int aoff = (k0 < 1024) ? k0 : (k0 - 1024);
        const int boff = (k0 < 512)  ? k0 : (k0 - 512);
        __builtin_amdgcn_global_load_lds(
            (const __attribute__((address_space(1))) void*)(Ag0 + aoff),
            (__attribute__((address_space(3))) void*)&Als[buf][ls0], 16, 0, 0);
        __builtin_amdgcn_global_load_lds(
            (const __attribute__((address_space(1))) void*)(Ag1 + aoff),
            (__attribute__((address_space(3))) void*)&Als[buf][ls1], 16, 0, 0);
        __builtin_amdgcn_global_load_lds(
            (const __attribute__((address_space(1))) void*)(Bg0 + boff),
            (__attribute__((address_space(3))) void*)&Bls[buf][ls0], 16, 0, 0);
        __builtin_amdgcn_global_load_lds(
            (const __attribute__((address_space(1))) void*)(Bg1 + boff),
            (__attribute__((address_space(3))) void*)&Bls[buf][ls1], 16, 0, 0);
    };

    prefetch(0, 0);

    f4 acc[4][4] = {};

    for (int k0 = 0; k0 < 1536; k0 += 32) {
        const int cur = (k0 >> 5) & 1;
        __syncthreads();                 // drains prefetch(cur); safe vs dbuf
        if (k0 + 32 < 1536) prefetch(cur ^ 1, k0 + 32);

        s8 a[4], b[4];
        #pragma unroll
        for (int i = 0; i < 4; ++i)
            a[i] = *(const s8*)&Als[cur][((wm >> 4) + i) * 512 + rslot];
        #pragma unroll
        for (int j = 0; j < 4; ++j)
            b[j] = *(const s8*)&Bls[cur][((wn >> 4) + j) * 512 + rslot];
        #pragma unroll
        for (int i = 0; i < 4; ++i)
            #pragma unroll
            for (int j = 0; j < 4; ++j)
                acc[i][j] = __builtin_amdgcn_mfma_f32_16x16x32_bf16(
                    a[i], b[j], acc[i][j], 0, 0, 0);
    }

    const int col = lane & 15;
    const int rb  = (lane >> 4) * 4;
    #pragma unroll
    for (int j = 0; j < 4; ++j) {
        float bj = bias[bn + wn + j * 16 + col];
        #pragma unroll
        for (int i = 0; i < 4; ++i) {
            size_t base = (size_t)(bm + wm + i * 16 + rb) * N + (bn + wn + j * 16 + col);
            #pragma unroll
            for (int r = 0; r < 4; ++r)
                C[base + (size_t)r * N] = acc[i][j][r] + bj;
        }
    }
}

// ---------------------------------------------------------------------------
// Banded MHA. One wave per (b,h,i). backward = dir0 + z.
// ---------------------------------------------------------------------------
__global__ __launch_bounds__(256) void banded_attn(
    const float* __restrict__ Q0, const float* __restrict__ Q1,
    unsigned short* __restrict__ O0, unsigned short* __restrict__ O1,
    int dir0)
{
    const float* QKV = blockIdx.z ? Q1 : Q0;
    unsigned short* O2 = blockIdx.z ? O1 : O0;
    int backward = dir0 + blockIdx.z;

    int w    = blockIdx.x * 4 + (threadIdx.x >> 6);
    int lane = threadIdx.x & 63;
    int i  = w % PAD;
    int bh = w / PAD;
    int h  = bh & (NHEADS - 1);
    int b  = bh / NHEADS;

    int jlo, n;
    if (backward) { jlo = i; n = min(WIDTH + 2, PAD - i); }
    else          { jlo = max(0, i - WIDTH - 1); n = i - jlo + 1; }

    const int s = lane >> 4;
    const int d = lane & 15;
    const size_t rowbase = (size_t)(b * PAD) * 1536;
    const int colq = h * DK;

    float4 q4 = *(const float4*)(QKV + rowbase + (size_t)i * 1536 + colq + 4 * d);

    float sc[5];
    #pragma unroll
    for (int m = 0; m < 5; ++m) {
        int t  = 4 * m + s;
        int tc = t < n ? t : n - 1;
        float4 kv = *(const float4*)(QKV + rowbase + (size_t)(jlo + tc) * 1536
                                     + 512 + colq + 4 * d);
        float p = q4.x * kv.x + q4.y * kv.y + q4.z * kv.z + q4.w * kv.w;
        p += __shfl_xor(p, 1);
        p += __shfl_xor(p, 2);
        p += __shfl_xor(p, 4);
        p += __shfl_xor(p, 8);
        sc[m] = p * 0.125f;
    }

    float sv[WIDTH + 2];
    #pragma unroll
    for (int t = 0; t < WIDTH + 2; ++t) {
        float v = __shfl(sc[t >> 2], (t & 3) << 4);
        sv[t] = (t < n) ? v : -1e30f;
    }
    float mx = sv[0];
    #pragma unroll
    for (int t = 1; t < WIDTH + 2; ++t) mx = fmaxf(mx, sv[t]);
    float denom = 0.f;
    #pragma unroll
    for (int t = 0; t < WIDTH + 2; ++t) { sv[t] = __expf(sv[t] - mx); denom += sv[t]; }
    float inv = 1.0f / denom;

    float od0 = 0.f, od1 = 0.f;
    #pragma unroll
    for (int t = 0; t < WIDTH + 2; t += 2) {
        int tc0 = t     < n ? t     : n - 1;
        int tc1 = t + 1 < n ? t + 1 : n - 1;
        od0 += sv[t]     * QKV[rowbase + (size_t)(jlo + tc0) * 1536 + 1024 + colq + lane];
        od1 += sv[t + 1] * QKV[rowbase + (size_t)(jlo + tc1) * 1536 + 1024 + colq + lane];
    }
    float od = (od0 + od1) * inv;

    unsigned short hh, ll;
    split2(od, hh, ll);
    size_t ro = (size_t)(b * PAD + i) * RS + colq + lane;
    O2[ro] = hh; O2[ro + 512] = ll;
}

// ---------------------------------------------------------------------------
__global__ __launch_bounds__(256) void rel_combine(
    const float* __restrict__ a0, const float* __restrict__ a1,
    const float* __restrict__ w0, const float* __restrict__ w1,
    unsigned short* __restrict__ f0, unsigned short* __restrict__ f1,
    int off0, int off1)
{
    const float* att = blockIdx.z ? a1 : a0;
    const float* w   = blockIdx.z ? w1 : w0;
    unsigned short* fo2 = blockIdx.z ? f1 : f0;
    int offset = blockIdx.z ? off1 : off0;

    int idx = blockIdx.x * 256 + threadIdx.x;   // over B*S*128
    int c4 = idx & 127;
    int rest = idx >> 7;
    int t = rest & (S - 1);
    int b = rest >> 10;

    const float* rowbase = att + (size_t)b * PAD * HID + c4 * 4;
    float4 acc = *(const float4*)(rowbase + (size_t)(WIDTH + t) * HID);
    #pragma unroll
    for (int k = 0; k <= WIDTH; ++k) {
        float wk = w[k];
        float4 xv = *(const float4*)(rowbase + (size_t)(offset + k + t) * HID);
        acc.x += wk * xv.x; acc.y += wk * xv.y;
        acc.z += wk * xv.z; acc.w += wk * xv.w;
    }
    store_split4(fo2 + ((size_t)b * S + t) * RS + c4 * 4, acc);
}

// ---------------------------------------------------------------------------
__global__ __launch_bounds__(256) void highway_gate(
    const unsigned short* __restrict__ x0, const unsigned short* __restrict__ x1,
    const float* __restrict__ p0, const float* __restrict__ p1,
    float* __restrict__ of0, float* __restrict__ of1,
    unsigned short* __restrict__ o20, unsigned short* __restrict__ o21,
    float* __restrict__ os0, float* __restrict__ os1)
{
    const unsigned short* x2 = blockIdx.z ? x1 : x0;
    const float* proj        = blockIdx.z ? p1 : p0;
    float* outf              = blockIdx.z ? of1 : of0;
    unsigned short* out2     = blockIdx.z ? o21 : o20;
    float* oslice            = blockIdx.z ? os1 : os0;

    int idx = blockIdx.x * 256 + threadIdx.x;   // over B*S*128
    int c4 = idx & 127;
    int r  = idx >> 7;
    const unsigned short* xr = x2 + (size_t)r * RS + c4 * 4;
    uint2 hp = *(const uint2*)(xr);
    uint2 lp = *(const uint2*)(xr + 512);
    float4 xv;
    xv.x = bf2f((unsigned short)(hp.x & 0xffff)) + bf2f((unsigned short)(lp.x & 0xffff));
    xv.y = bf2f((unsigned short)(hp.x >> 16))    + bf2f((unsigned short)(lp.x >> 16));
    xv.z = bf2f((unsigned short)(hp.y & 0xffff)) + bf2f((unsigned short)(lp.y & 0xffff));
    xv.w = bf2f((unsigned short)(hp.y >> 16))    + bf2f((unsigned short)(lp.y >> 16));

    float4 nl = *(const float4*)(proj + (size_t)r * (2 * HID) + c4 * 4);
    float4 g  = *(const float4*)(proj + (size_t)r * (2 * HID) + HID + c4 * 4);
    float4 o;
    float sg;
    sg = 1.f / (1.f + __expf(-g.x)); o.x = sg * xv.x + (1.f - sg) * fmaxf(nl.x, 0.f);
    sg = 1.f / (1.f + __expf(-g.y)); o.y = sg * xv.y + (1.f - sg) * fmaxf(nl.y, 0.f);
    sg = 1.f / (1.f + __expf(-g.z)); o.z = sg * xv.z + (1.f - sg) * fmaxf(nl.z, 0.f);
    sg = 1.f / (1.f + __expf(-g.w)); o.w = sg * xv.w + (1.f - sg) * fmaxf(nl.w, 0.f);
    if (outf)   *(float4*)(outf + (size_t)idx * 4) = o;
    if (out2)   store_split4(out2 + (size_t)r * RS + c4 * 4, o);
    if (oslice) *(float4*)(oslice + (size_t)r * (2 * HID) + c4 * 4) = o;
}

// ---------------------------------------------------------------------------
extern "C" void kernel_launch(void* const* d_in, const int* in_sizes, int n_in,
                              void* d_out, int out_size, void* d_ws, size_t ws_size,
                              hipStream_t stream)
{
    const float* inputs   = (const float*)d_in[0];
    const float* fw_lin_w = (const float*)d_in[2];
    const float* fw_lin_b = (const float*)d_in[3];
    const float* bw_lin_w = (const float*)d_in[4];
    const float* bw_lin_b = (const float*)d_in[5];
    const float* fw_hw_w  = (const float*)d_in[6];
    const float* fw_hw_b  = (const float*)d_in[7];
    const float* bw_hw_w  = (const float*)d_in[8];
    const float* bw_hw_b  = (const float*)d_in[9];
    const float* fw_pad   = (const float*)d_in[10];
    const float* bw_pad   = (const float*)d_in[11];
    const float* fw_rel   = (const float*)d_in[12];
    const float* bw_rel   = (const float*)d_in[13];
    float* out = (float*)d_out;
    float* ws  = (float*)d_ws;

    const size_t BSH  = (size_t)B * S * HID;      // 2,097,152 floats
    const size_t QKVF = (size_t)B * PAD * 1536;   // 6,488,064 floats per dir
    const int MP = B * PAD;                       // 4224
    const int MS = B * S;                         // 4096

    const size_t GROUPED_FLOATS = 2 * QKVF + (2 * (size_t)MP * RS + 2 * (size_t)1536 * RS) / 2;
    const size_t WALL_FLOATS    = 2 * QKVF + (2 * (size_t)MP * RS + (size_t)2 * 8192 * RS) / 2;
    const bool wall    = ws_size >= WALL_FLOATS * 4;
    const bool grouped = wall || ws_size >= GROUPED_FLOATS * 4;
    const int G = grouped ? 2 : 1;

    float* f  = ws;
    float* bk = f + BSH;

    float* QKV[2]; float* ATT[2]; float* HWP[2];
    unsigned short* ACT2[2]; unsigned short* W2[2];
    unsigned short* w2all = nullptr;
    if (grouped) {
        QKV[0] = ws;             QKV[1] = ws + QKVF;
        float* extra = ws + 2 * BSH;
        ATT[0] = extra;          ATT[1] = extra + (size_t)MP * HID;
        HWP[0] = extra;          HWP[1] = extra + (size_t)MS * 1024;
        unsigned short* a2 = (unsigned short*)(ws + 2 * QKVF);
        ACT2[0] = a2;            ACT2[1] = a2 + (size_t)MP * RS;
        unsigned short* w2 = a2 + 2 * (size_t)MP * RS;
        if (wall) { w2all = w2; W2[0] = W2[1] = nullptr; }
        else      { W2[0] = w2; W2[1] = w2 + (size_t)1536 * RS; }
    } else {
        float* qkvS = bk + BSH;
        QKV[0] = QKV[1] = qkvS;
        ATT[0] = ATT[1] = qkvS;
        HWP[0] = HWP[1] = qkvS;
        unsigned short* a2 = (unsigned short*)(qkvS + QKVF);
        ACT2[0] = ACT2[1] = a2;
        W2[0] = W2[1] = a2 + (size_t)MP * RS;
    }

    if (wall) {
        conv_all<<<dim3(8192 * 128 / 256, 1, 2), 256, 0, stream>>>(
            fw_lin_w, bw_lin_w, fw_hw_w, bw_hw_w, w2all);
    }
    // w2all row offsets per (dir,l): QKV=0, out=1536, hw_i=2048+1024*i
    auto WB = [&](int dir, int l, int seg) -> unsigned short* {
        return w2all + ((size_t)dir * 8192 + (size_t)l * 4096 + seg) * RS;
    };

    for (int l = 0; l < NLAYERS; ++l) {
        const float* LINW[2] = {fw_lin_w + (size_t)l * 4 * HID * HID,
                                bw_lin_w + (size_t)l * 4 * HID * HID};
        const float* LINB[2] = {fw_lin_b + (size_t)l * 4 * HID,
                                bw_lin_b + (size_t)l * 4 * HID};
        const float* HWW[2]  = {fw_hw_w + (size_t)l * NHW * 2 * HID * HID,
                                bw_hw_w + (size_t)l * NHW * 2 * HID * HID};
        const float* HWB[2]  = {fw_hw_b + (size_t)l * NHW * 2 * HID,
                                bw_hw_b + (size_t)l * NHW * 2 * HID};
        const float* RELW[2] = {fw_rel + (size_t)l * (WIDTH + 1),
                                bw_rel + (size_t)l * (WIDTH + 1)};
        const float* front = fw_pad + (size_t)l * WIDTH * HID;
        const float* back  = bw_pad + (size_t)l * WIDTH * HID;
        float* DST[2] = {f, bk};
        float* OSL[2] = {out + (size_t)l * B * S * 2 * HID,
                         out + (size_t)l * B * S * 2 * HID + HID};
        const float* SRC[2] = {(l == 0) ? inputs : f, (l == 0) ? inputs : bk};

        for (int d0 = 0; d0 < 2; d0 += G) {
            const int dB = (G == 2) ? 1 : d0;

            build_pad_split<<<dim3(MP * 128 / 256, 1, G), 256, 0, stream>>>(
                SRC[d0], SRC[dB], front, back, ACT2[0], ACT2[1]);

            unsigned short *wq0, *wq1;
            if (wall) { wq0 = WB(d0, l, 0); wq1 = WB(dB, l, 0); }
            else {
                conv_w<<<dim3(1536 * 128 / 256, 1, G), 256, 0, stream>>>(
                    LINW[d0], LINW[dB], W2[0], W2[1]);
                wq0 = W2[0]; wq1 = W2[1];
            }
            gemm_split<<<dim3(1536 / 128, MP / 128, G), 256, 0, stream>>>(
                ACT2[0], wq0, LINB[d0], QKV[0],
                ACT2[1], wq1, LINB[dB], QKV[1], 1536);

            banded_attn<<<dim3(B * NHEADS * PAD / 4, 1, G), 256, 0, stream>>>(
                QKV[0], QKV[1], ACT2[0], ACT2[1], d0);

            unsigned short *wo0, *wo1;
            if (wall) { wo0 = WB(d0, l, 1536); wo1 = WB(dB, l, 1536); }
            else {
                conv_w<<<dim3(512 * 128 / 256, 1, G), 256, 0, stream>>>(
                    LINW[d0] + 3 * (size_t)HID * HID, LINW[dB] + 3 * (size_t)HID * HID,
                    W2[0], W2[1]);
                wo0 = W2[0]; wo1 = W2[1];
            }
            gemm_split<<<dim3(512 / 128, MP / 128, G), 256, 0, stream>>>(
                ACT2[0], wo0, LINB[d0] + 3 * HID, ATT[0],
                ACT2[1], wo1, LINB[dB] + 3 * HID, ATT[1], 512);

            rel_combine<<<dim3(MS * 128 / 256, 1, G), 256, 0, stream>>>(
                ATT[0], ATT[1], RELW[d0], RELW[dB], ACT2[0], ACT2[1],
                d0 * WIDTH, dB * WIDTH);

            for (int i = 0; i < NHW; ++i) {
                unsigned short *wh0, *wh1;
                if (wall) { wh0 = WB(d0, l, 2048 + 1024 * i); wh1 = WB(dB, l, 2048 + 1024 * i); }
                else {
                    conv_w<<<dim3(1024 * 128 / 256, 1, G), 256, 0, stream>>>(
                        HWW[d0] + (size_t)i * 2 * HID * HID,
                        HWW[dB] + (size_t)i * 2 * HID * HID, W2[0], W2[1]);
                    wh0 = W2[0]; wh1 = W2[1];
                }
                gemm_split<<<dim3(1024 / 128, MS / 128, G), 256, 0, stream>>>(
                    ACT2[0], wh0, HWB[d0] + (size_t)i * 2 * HID, HWP[0],
                    ACT2[1], wh1, HWB[dB] + (size_t)i * 2 * HID, HWP[1], 1024);
                const bool last = (i == NHW - 1);
                highway_gate<<<dim3(MS * 128 / 256, 1, G), 256, 0, stream>>>(
                    ACT2[0], ACT2[1], HWP[0], HWP[1],
                    last ? DST[d0] : (float*)nullptr,
                    last ? DST[dB] : (float*)nullptr,
                    last ? (unsigned short*)nullptr : ACT2[0],
                    last ? (unsigned short*)nullptr : ACT2[1],
                    last ? OSL[d0] : (float*)nullptr,
                    last ? OSL[dB] : (float*)nullptr);
            }
        }
    }
}

// Round 9
// 581.727 us; speedup vs baseline: 1.2035x; 1.2035x over previous
//
#include <hip/hip_runtime.h>

using s8 = __attribute__((ext_vector_type(8))) short;
using f4 = __attribute__((ext_vector_type(4))) float;

constexpr int WIDTH   = 16;
constexpr int HID     = 512;
constexpr int NHEADS  = 8;
constexpr int DK      = 64;
constexpr int NLAYERS = 2;
constexpr int NHW     = 2;
constexpr int B       = 4;
constexpr int S       = 1024;
constexpr int PAD     = S + 2 * WIDTH;   // 1056
constexpr int RS      = 1024;            // split row stride (shorts): [H(512)|L(512)]
constexpr int K2      = 1024;            // virtual K: A=[H|L], B=[H|H]
                                         // -> Ah*Bh + Al*Bh (drops Ah*Bl ~1e-3 absmax)

__device__ inline unsigned short f2bf(float x) {
    union { float f; unsigned u; } c; c.f = x;
    unsigned r = c.u + 0x7fffu + ((c.u >> 16) & 1u);
    return (unsigned short)(r >> 16);
}
__device__ inline float bf2f(unsigned short h) {
    union { float f; unsigned u; } c; c.u = ((unsigned)h) << 16; return c.f;
}
__device__ inline void split2(float x, unsigned short& h, unsigned short& l) {
    h = f2bf(x);
    l = f2bf(x - bf2f(h));
}
__device__ inline void store_split4(unsigned short* dst, float4 v) {
    unsigned short h[4], l[4];
    split2(v.x, h[0], l[0]); split2(v.y, h[1], l[1]);
    split2(v.z, h[2], l[2]); split2(v.w, h[3], l[3]);
    uint2 hp, lp;
    hp.x = h[0] | ((unsigned)h[1] << 16); hp.y = h[2] | ((unsigned)h[3] << 16);
    lp.x = l[0] | ((unsigned)l[1] << 16); lp.y = l[2] | ((unsigned)l[3] << 16);
    *(uint2*)(dst)       = hp;
    *(uint2*)(dst + 512) = lp;
}

// ---------------------------------------------------------------------------
__global__ __launch_bounds__(256) void build_pad_split(
    const float* __restrict__ src0, const float* __restrict__ src1,
    const float* __restrict__ front, const float* __restrict__ back,
    unsigned short* __restrict__ d0, unsigned short* __restrict__ d1)
{
    const float* x = blockIdx.z ? src1 : src0;
    unsigned short* xp2 = blockIdx.z ? d1 : d0;
    int idx = blockIdx.x * 256 + threadIdx.x;   // over B*PAD*128
    int c4 = idx & 127;
    int rest = idx >> 7;
    int p = rest % PAD;
    int b = rest / PAD;
    float4 val;
    if (p < WIDTH) {
        val = *(const float4*)(front + (size_t)p * HID + c4 * 4);
    } else if (p < WIDTH + S) {
        val = *(const float4*)(x + ((size_t)b * S + (p - WIDTH)) * HID + c4 * 4);
    } else {
        val = *(const float4*)(back + (size_t)(p - WIDTH - S) * HID + c4 * 4);
    }
    store_split4(xp2 + (size_t)(b * PAD + p) * RS + c4 * 4, val);
}

// ---------------------------------------------------------------------------
// per-use weight conversion (fallback paths): fp32 [R,HID] -> split [R,RS]
// ---------------------------------------------------------------------------
__global__ __launch_bounds__(256) void conv_w(
    const float* __restrict__ s0, const float* __restrict__ s1,
    unsigned short* __restrict__ w0, unsigned short* __restrict__ w1)
{
    const float* src = blockIdx.z ? s1 : s0;
    unsigned short* dst = blockIdx.z ? w1 : w0;
    int idx = blockIdx.x * 256 + threadIdx.x;
    int c4 = idx & 127;
    int r  = idx >> 7;
    float4 v = *(const float4*)(src + (size_t)r * HID + c4 * 4);
    store_split4(dst + (size_t)r * RS + c4 * 4, v);
}

// ---------------------------------------------------------------------------
// one-shot conversion of ALL weights -> w2all [2 dirs][8192 rows][RS]
// per (dir,layer): rows 0..2047 = lin_w (q,k,v,out stacked), 2048..4095 = hw_w
// ---------------------------------------------------------------------------
__global__ __launch_bounds__(256) void conv_all(
    const float* __restrict__ fw_lin_w, const float* __restrict__ bw_lin_w,
    const float* __restrict__ fw_hw_w,  const float* __restrict__ bw_hw_w,
    unsigned short* __restrict__ w2all)
{
    int idx = blockIdx.x * 256 + threadIdx.x;   // over 8192*128
    int c4 = idx & 127;
    int r  = idx >> 7;          // 0..8191
    int l  = r >> 12;           // layer
    int rr = r & 4095;
    const float* lin = blockIdx.z ? bw_lin_w : fw_lin_w;
    const float* hw  = blockIdx.z ? bw_hw_w  : fw_hw_w;
    const float* src = (rr < 2048)
        ? lin + ((size_t)l * 2048 + rr) * HID
        : hw  + ((size_t)l * 2048 + (rr - 2048)) * HID;
    float4 v = *(const float4*)(src + c4 * 4);
    store_split4(w2all + ((size_t)blockIdx.z * 8192 + r) * RS + c4 * 4, v);
}

// ---------------------------------------------------------------------------
// Split-bf16 MFMA GEMM (NT), single-buffered (R8 dbuf regressed: 2x LDS cut
// occupancy, barrier still drained the prefetch). Virtual K2=1024:
// A segs [H,L]: aoff = k0;  B segs [H,H]: boff = k0<512 ? k0 : k0-512.
// Staging keeps the R7 permuted-slot swizzle: coalesced fill (4 lanes per
// 64B line) + conflict-free fragment ds_read_b128 (2-way only, free).
// ---------------------------------------------------------------------------
__global__ __launch_bounds__(256) void gemm_split(
    const unsigned short* __restrict__ A0, const unsigned short* __restrict__ B0,
    const float* __restrict__ bias0, float* __restrict__ C0,
    const unsigned short* __restrict__ A1, const unsigned short* __restrict__ B1,
    const float* __restrict__ bias1, float* __restrict__ C1,
    int N)
{
    const unsigned short* A  = blockIdx.z ? A1 : A0;
    const unsigned short* Bw = blockIdx.z ? B1 : B0;
    const float* bias        = blockIdx.z ? bias1 : bias0;
    float* C                 = blockIdx.z ? C1 : C0;

    __shared__ unsigned short Als[128 * 32];
    __shared__ unsigned short Bls[128 * 32];

    const int tid  = threadIdx.x;
    const int wave = tid >> 6;
    const int lane = tid & 63;
    const int bm = blockIdx.y * 128;
    const int bn = blockIdx.x * 128;
    const int wm = (wave >> 1) * 64;
    const int wn = (wave & 1) * 64;

    const int c0 = wave * 2, c1 = wave * 2 + 1;
    const int lr = lane >> 2;                      // row within 16-row chunk
    const int kg = ((lane & 3) + (lr >> 1)) & 3;   // permuted k-granule
    const int sr0 = c0 * 16 + lr;
    const int sr1 = c1 * 16 + lr;
    const int sc  = kg * 8;
    const unsigned short* Ag0 = A  + (size_t)(bm + sr0) * RS + sc;
    const unsigned short* Ag1 = A  + (size_t)(bm + sr1) * RS + sc;
    const unsigned short* Bg0 = Bw + (size_t)(bn + sr0) * RS + sc;
    const unsigned short* Bg1 = Bw + (size_t)(bn + sr1) * RS + sc;
    const int ls0 = c0 * 512;
    const int ls1 = c1 * 512;

    const int fr = lane & 15;
    const int q  = lane >> 4;
    const int rslot = (4 * fr + ((q - (fr >> 1)) & 3)) * 8;

    f4 acc[4][4] = {};

    for (int k0 = 0; k0 < K2; k0 += 32) {
        const int aoff = k0;
        const int boff = (k0 < 512) ? k0 : (k0 - 512);
        __builtin_amdgcn_global_load_lds(
            (const __attribute__((address_space(1))) void*)(Ag0 + aoff),
            (__attribute__((address_space(3))) void*)&Als[ls0], 16, 0, 0);
        __builtin_amdgcn_global_load_lds(
            (const __attribute__((address_space(1))) void*)(Ag1 + aoff),
            (__attribute__((address_space(3))) void*)&Als[ls1], 16, 0, 0);
        __builtin_amdgcn_global_load_lds(
            (const __attribute__((address_space(1))) void*)(Bg0 + boff),
            (__attribute__((address_space(3))) void*)&Bls[ls0], 16, 0, 0);
        __builtin_amdgcn_global_load_lds(
            (const __attribute__((address_space(1))) void*)(Bg1 + boff),
            (__attribute__((address_space(3))) void*)&Bls[ls1], 16, 0, 0);
        __syncthreads();

        s8 a[4], b[4];
        #pragma unroll
        for (int i = 0; i < 4; ++i)
            a[i] = *(const s8*)&Als[((wm >> 4) + i) * 512 + rslot];
        #pragma unroll
        for (int j = 0; j < 4; ++j)
            b[j] = *(const s8*)&Bls[((wn >> 4) + j) * 512 + rslot];
        #pragma unroll
        for (int i = 0; i < 4; ++i)
            #pragma unroll
            for (int j = 0; j < 4; ++j)
                acc[i][j] = __builtin_amdgcn_mfma_f32_16x16x32_bf16(
                    a[i], b[j], acc[i][j], 0, 0, 0);
        __syncthreads();
    }

    const int col = lane & 15;
    const int rb  = (lane >> 4) * 4;
    #pragma unroll
    for (int j = 0; j < 4; ++j) {
        float bj = bias[bn + wn + j * 16 + col];
        #pragma unroll
        for (int i = 0; i < 4; ++i) {
            size_t base = (size_t)(bm + wm + i * 16 + rb) * N + (bn + wn + j * 16 + col);
            #pragma unroll
            for (int r = 0; r < 4; ++r)
                C[base + (size_t)r * N] = acc[i][j][r] + bj;
        }
    }
}

// ---------------------------------------------------------------------------
// Banded MHA. One wave per (b,h,i). backward = dir0 + z.
// ---------------------------------------------------------------------------
__global__ __launch_bounds__(256) void banded_attn(
    const float* __restrict__ Q0, const float* __restrict__ Q1,
    unsigned short* __restrict__ O0, unsigned short* __restrict__ O1,
    int dir0)
{
    const float* QKV = blockIdx.z ? Q1 : Q0;
    unsigned short* O2 = blockIdx.z ? O1 : O0;
    int backward = dir0 + blockIdx.z;

    int w    = blockIdx.x * 4 + (threadIdx.x >> 6);
    int lane = threadIdx.x & 63;
    int i  = w % PAD;
    int bh = w / PAD;
    int h  = bh & (NHEADS - 1);
    int b  = bh / NHEADS;

    int jlo, n;
    if (backward) { jlo = i; n = min(WIDTH + 2, PAD - i); }
    else          { jlo = max(0, i - WIDTH - 1); n = i - jlo + 1; }

    const int s = lane >> 4;
    const int d = lane & 15;
    const size_t rowbase = (size_t)(b * PAD) * 1536;
    const int colq = h * DK;

    float4 q4 = *(const float4*)(QKV + rowbase + (size_t)i * 1536 + colq + 4 * d);

    float sc[5];
    #pragma unroll
    for (int m = 0; m < 5; ++m) {
        int t  = 4 * m + s;
        int tc = t < n ? t : n - 1;
        float4 kv = *(const float4*)(QKV + rowbase + (size_t)(jlo + tc) * 1536
                                     + 512 + colq + 4 * d);
        float p = q4.x * kv.x + q4.y * kv.y + q4.z * kv.z + q4.w * kv.w;
        p += __shfl_xor(p, 1);
        p += __shfl_xor(p, 2);
        p += __shfl_xor(p, 4);
        p += __shfl_xor(p, 8);
        sc[m] = p * 0.125f;
    }

    float sv[WIDTH + 2];
    #pragma unroll
    for (int t = 0; t < WIDTH + 2; ++t) {
        float v = __shfl(sc[t >> 2], (t & 3) << 4);
        sv[t] = (t < n) ? v : -1e30f;
    }
    float mx = sv[0];
    #pragma unroll
    for (int t = 1; t < WIDTH + 2; ++t) mx = fmaxf(mx, sv[t]);
    float denom = 0.f;
    #pragma unroll
    for (int t = 0; t < WIDTH + 2; ++t) { sv[t] = __expf(sv[t] - mx); denom += sv[t]; }
    float inv = 1.0f / denom;

    float od0 = 0.f, od1 = 0.f;
    #pragma unroll
    for (int t = 0; t < WIDTH + 2; t += 2) {
        int tc0 = t     < n ? t     : n - 1;
        int tc1 = t + 1 < n ? t + 1 : n - 1;
        od0 += sv[t]     * QKV[rowbase + (size_t)(jlo + tc0) * 1536 + 1024 + colq + lane];
        od1 += sv[t + 1] * QKV[rowbase + (size_t)(jlo + tc1) * 1536 + 1024 + colq + lane];
    }
    float od = (od0 + od1) * inv;

    unsigned short hh, ll;
    split2(od, hh, ll);
    size_t ro = (size_t)(b * PAD + i) * RS + colq + lane;
    O2[ro] = hh; O2[ro + 512] = ll;
}

// ---------------------------------------------------------------------------
__global__ __launch_bounds__(256) void rel_combine(
    const float* __restrict__ a0, const float* __restrict__ a1,
    const float* __restrict__ w0, const float* __restrict__ w1,
    unsigned short* __restrict__ f0, unsigned short* __restrict__ f1,
    int off0, int off1)
{
    const float* att = blockIdx.z ? a1 : a0;
    const float* w   = blockIdx.z ? w1 : w0;
    unsigned short* fo2 = blockIdx.z ? f1 : f0;
    int offset = blockIdx.z ? off1 : off0;

    int idx = blockIdx.x * 256 + threadIdx.x;   // over B*S*128
    int c4 = idx & 127;
    int rest = idx >> 7;
    int t = rest & (S - 1);
    int b = rest >> 10;

    const float* rowbase = att + (size_t)b * PAD * HID + c4 * 4;
    float4 acc = *(const float4*)(rowbase + (size_t)(WIDTH + t) * HID);
    #pragma unroll
    for (int k = 0; k <= WIDTH; ++k) {
        float wk = w[k];
        float4 xv = *(const float4*)(rowbase + (size_t)(offset + k + t) * HID);
        acc.x += wk * xv.x; acc.y += wk * xv.y;
        acc.z += wk * xv.z; acc.w += wk * xv.w;
    }
    store_split4(fo2 + ((size_t)b * S + t) * RS + c4 * 4, acc);
}

// ---------------------------------------------------------------------------
__global__ __launch_bounds__(256) void highway_gate(
    const unsigned short* __restrict__ x0, const unsigned short* __restrict__ x1,
    const float* __restrict__ p0, const float* __restrict__ p1,
    float* __restrict__ of0, float* __restrict__ of1,
    unsigned short* __restrict__ o20, unsigned short* __restrict__ o21,
    float* __restrict__ os0, float* __restrict__ os1)
{
    const unsigned short* x2 = blockIdx.z ? x1 : x0;
    const float* proj        = blockIdx.z ? p1 : p0;
    float* outf              = blockIdx.z ? of1 : of0;
    unsigned short* out2     = blockIdx.z ? o21 : o20;
    float* oslice            = blockIdx.z ? os1 : os0;

    int idx = blockIdx.x * 256 + threadIdx.x;   // over B*S*128
    int c4 = idx & 127;
    int r  = idx >> 7;
    const unsigned short* xr = x2 + (size_t)r * RS + c4 * 4;
    uint2 hp = *(const uint2*)(xr);
    uint2 lp = *(const uint2*)(xr + 512);
    float4 xv;
    xv.x = bf2f((unsigned short)(hp.x & 0xffff)) + bf2f((unsigned short)(lp.x & 0xffff));
    xv.y = bf2f((unsigned short)(hp.x >> 16))    + bf2f((unsigned short)(lp.x >> 16));
    xv.z = bf2f((unsigned short)(hp.y & 0xffff)) + bf2f((unsigned short)(lp.y & 0xffff));
    xv.w = bf2f((unsigned short)(hp.y >> 16))    + bf2f((unsigned short)(lp.y >> 16));

    float4 nl = *(const float4*)(proj + (size_t)r * (2 * HID) + c4 * 4);
    float4 g  = *(const float4*)(proj + (size_t)r * (2 * HID) + HID + c4 * 4);
    float4 o;
    float sg;
    sg = 1.f / (1.f + __expf(-g.x)); o.x = sg * xv.x + (1.f - sg) * fmaxf(nl.x, 0.f);
    sg = 1.f / (1.f + __expf(-g.y)); o.y = sg * xv.y + (1.f - sg) * fmaxf(nl.y, 0.f);
    sg = 1.f / (1.f + __expf(-g.z)); o.z = sg * xv.z + (1.f - sg) * fmaxf(nl.z, 0.f);
    sg = 1.f / (1.f + __expf(-g.w)); o.w = sg * xv.w + (1.f - sg) * fmaxf(nl.w, 0.f);
    if (outf)   *(float4*)(outf + (size_t)idx * 4) = o;
    if (out2)   store_split4(out2 + (size_t)r * RS + c4 * 4, o);
    if (oslice) *(float4*)(oslice + (size_t)r * (2 * HID) + c4 * 4) = o;
}

// ---------------------------------------------------------------------------
extern "C" void kernel_launch(void* const* d_in, const int* in_sizes, int n_in,
                              void* d_out, int out_size, void* d_ws, size_t ws_size,
                              hipStream_t stream)
{
    const float* inputs   = (const float*)d_in[0];
    const float* fw_lin_w = (const float*)d_in[2];
    const float* fw_lin_b = (const float*)d_in[3];
    const float* bw_lin_w = (const float*)d_in[4];
    const float* bw_lin_b = (const float*)d_in[5];
    const float* fw_hw_w  = (const float*)d_in[6];
    const float* fw_hw_b  = (const float*)d_in[7];
    const float* bw_hw_w  = (const float*)d_in[8];
    const float* bw_hw_b  = (const float*)d_in[9];
    const float* fw_pad   = (const float*)d_in[10];
    const float* bw_pad   = (const float*)d_in[11];
    const float* fw_rel   = (const float*)d_in[12];
    const float* bw_rel   = (const float*)d_in[13];
    float* out = (float*)d_out;
    float* ws  = (float*)d_ws;

    const size_t BSH  = (size_t)B * S * HID;      // 2,097,152 floats
    const size_t QKVF = (size_t)B * PAD * 1536;   // 6,488,064 floats per dir
    const int MP = B * PAD;                       // 4224
    const int MS = B * S;                         // 4096

    const size_t GROUPED_FLOATS = 2 * QKVF + (2 * (size_t)MP * RS + 2 * (size_t)1536 * RS) / 2;
    const size_t WALL_FLOATS    = 2 * QKVF + (2 * (size_t)MP * RS + (size_t)2 * 8192 * RS) / 2;
    const bool wall    = ws_size >= WALL_FLOATS * 4;
    const bool grouped = wall || ws_size >= GROUPED_FLOATS * 4;
    const int G = grouped ? 2 : 1;

    float* f  = ws;
    float* bk = f + BSH;

    float* QKV[2]; float* ATT[2]; float* HWP[2];
    unsigned short* ACT2[2]; unsigned short* W2[2];
    unsigned short* w2all = nullptr;
    if (grouped) {
        QKV[0] = ws;             QKV[1] = ws + QKVF;
        float* extra = ws + 2 * BSH;
        ATT[0] = extra;          ATT[1] = extra + (size_t)MP * HID;
        HWP[0] = extra;          HWP[1] = extra + (size_t)MS * 1024;
        unsigned short* a2 = (unsigned short*)(ws + 2 * QKVF);
        ACT2[0] = a2;            ACT2[1] = a2 + (size_t)MP * RS;
        unsigned short* w2 = a2 + 2 * (size_t)MP * RS;
        if (wall) { w2all = w2; W2[0] = W2[1] = nullptr; }
        else      { W2[0] = w2; W2[1] = w2 + (size_t)1536 * RS; }
    } else {
        float* qkvS = bk + BSH;
        QKV[0] = QKV[1] = qkvS;
        ATT[0] = ATT[1] = qkvS;
        HWP[0] = HWP[1] = qkvS;
        unsigned short* a2 = (unsigned short*)(qkvS + QKVF);
        ACT2[0] = ACT2[1] = a2;
        W2[0] = W2[1] = a2 + (size_t)MP * RS;
    }

    if (wall) {
        conv_all<<<dim3(8192 * 128 / 256, 1, 2), 256, 0, stream>>>(
            fw_lin_w, bw_lin_w, fw_hw_w, bw_hw_w, w2all);
    }
    // w2all row offsets per (dir,l): QKV=0, out=1536, hw_i=2048+1024*i
    auto WB = [&](int dir, int l, int seg) -> unsigned short* {
        return w2all + ((size_t)dir * 8192 + (size_t)l * 4096 + seg) * RS;
    };

    for (int l = 0; l < NLAYERS; ++l) {
        const float* LINW[2] = {fw_lin_w + (size_t)l * 4 * HID * HID,
                                bw_lin_w + (size_t)l * 4 * HID * HID};
        const float* LINB[2] = {fw_lin_b + (size_t)l * 4 * HID,
                                bw_lin_b + (size_t)l * 4 * HID};
        const float* HWW[2]  = {fw_hw_w + (size_t)l * NHW * 2 * HID * HID,
                                bw_hw_w + (size_t)l * NHW * 2 * HID * HID};
        const float* HWB[2]  = {fw_hw_b + (size_t)l * NHW * 2 * HID,
                                bw_hw_b + (size_t)l * NHW * 2 * HID};
        const float* RELW[2] = {fw_rel + (size_t)l * (WIDTH + 1),
                                bw_rel + (size_t)l * (WIDTH + 1)};
        const float* front = fw_pad + (size_t)l * WIDTH * HID;
        const float* back  = bw_pad + (size_t)l * WIDTH * HID;
        float* DST[2] = {f, bk};
        float* OSL[2] = {out + (size_t)l * B * S * 2 * HID,
                         out + (size_t)l * B * S * 2 * HID + HID};
        const float* SRC[2] = {(l == 0) ? inputs : f, (l == 0) ? inputs : bk};

        for (int d0 = 0; d0 < 2; d0 += G) {
            const int dB = (G == 2) ? 1 : d0;

            build_pad_split<<<dim3(MP * 128 / 256, 1, G), 256, 0, stream>>>(
                SRC[d0], SRC[dB], front, back, ACT2[0], ACT2[1]);

            unsigned short *wq0, *wq1;
            if (wall) { wq0 = WB(d0, l, 0); wq1 = WB(dB, l, 0); }
            else {
                conv_w<<<dim3(1536 * 128 / 256, 1, G), 256, 0, stream>>>(
                    LINW[d0], LINW[dB], W2[0], W2[1]);
                wq0 = W2[0]; wq1 = W2[1];
            }
            gemm_split<<<dim3(1536 / 128, MP / 128, G), 256, 0, stream>>>(
                ACT2[0], wq0, LINB[d0], QKV[0],
                ACT2[1], wq1, LINB[dB], QKV[1], 1536);

            banded_attn<<<dim3(B * NHEADS * PAD / 4, 1, G), 256, 0, stream>>>(
                QKV[0], QKV[1], ACT2[0], ACT2[1], d0);

            unsigned short *wo0, *wo1;
            if (wall) { wo0 = WB(d0, l, 1536); wo1 = WB(dB, l, 1536); }
            else {
                conv_w<<<dim3(512 * 128 / 256, 1, G), 256, 0, stream>>>(
                    LINW[d0] + 3 * (size_t)HID * HID, LINW[dB] + 3 * (size_t)HID * HID,
                    W2[0], W2[1]);
                wo0 = W2[0]; wo1 = W2[1];
            }
            gemm_split<<<dim3(512 / 128, MP / 128, G), 256, 0, stream>>>(
                ACT2[0], wo0, LINB[d0] + 3 * HID, ATT[0],
                ACT2[1], wo1, LINB[dB] + 3 * HID, ATT[1], 512);

            rel_combine<<<dim3(MS * 128 / 256, 1, G), 256, 0, stream>>>(
                ATT[0], ATT[1], RELW[d0], RELW[dB], ACT2[0], ACT2[1],
                d0 * WIDTH, dB * WIDTH);

            for (int i = 0; i < NHW; ++i) {
                unsigned short *wh0, *wh1;
                if (wall) { wh0 = WB(d0, l, 2048 + 1024 * i); wh1 = WB(dB, l, 2048 + 1024 * i); }
                else {
                    conv_w<<<dim3(1024 * 128 / 256, 1, G), 256, 0, stream>>>(
                        HWW[d0] + (size_t)i * 2 * HID * HID,
                        HWW[dB] + (size_t)i * 2 * HID * HID, W2[0], W2[1]);
                    wh0 = W2[0]; wh1 = W2[1];
                }
                gemm_split<<<dim3(1024 / 128, MS / 128, G), 256, 0, stream>>>(
                    ACT2[0], wh0, HWB[d0] + (size_t)i * 2 * HID, HWP[0],
                    ACT2[1], wh1, HWB[dB] + (size_t)i * 2 * HID, HWP[1], 1024);
                const bool last = (i == NHW - 1);
                highway_gate<<<dim3(MS * 128 / 256, 1, G), 256, 0, stream>>>(
                    ACT2[0], ACT2[1], HWP[0], HWP[1],
                    last ? DST[d0] : (float*)nullptr,
                    last ? DST[dB] : (float*)nullptr,
                    last ? (unsigned short*)nullptr : ACT2[0],
                    last ? (unsigned short*)nullptr : ACT2[1],
                    last ? OSL[d0] : (float*)nullptr,
                    last ? OSL[dB] : (float*)nullptr);
            }
        }
    }
}

// Round 10
// 564.270 us; speedup vs baseline: 1.2407x; 1.0309x over previous
//
#include <hip/hip_runtime.h>

using s8 = __attribute__((ext_vector_type(8))) short;
using f4 = __attribute__((ext_vector_type(4))) float;

constexpr int WIDTH   = 16;
constexpr int HID     = 512;
constexpr int NHEADS  = 8;
constexpr int DK      = 64;
constexpr int NLAYERS = 2;
constexpr int NHW     = 2;
constexpr int B       = 4;
constexpr int S       = 1024;
constexpr int PAD     = S + 2 * WIDTH;   // 1056
constexpr int RS      = 1024;            // split row stride (shorts): [H(512)|L(512)]
constexpr int K2      = 1024;            // virtual K: A=[H|L], B=[H|H] (drops Ah*Bl)

__device__ inline unsigned short f2bf(float x) {
    union { float f; unsigned u; } c; c.f = x;
    unsigned r = c.u + 0x7fffu + ((c.u >> 16) & 1u);
    return (unsigned short)(r >> 16);
}
__device__ inline float bf2f(unsigned short h) {
    union { float f; unsigned u; } c; c.u = ((unsigned)h) << 16; return c.f;
}
__device__ inline void split2(float x, unsigned short& h, unsigned short& l) {
    h = f2bf(x);
    l = f2bf(x - bf2f(h));
}
__device__ inline void store_split4(unsigned short* dst, float4 v) {
    unsigned short h[4], l[4];
    split2(v.x, h[0], l[0]); split2(v.y, h[1], l[1]);
    split2(v.z, h[2], l[2]); split2(v.w, h[3], l[3]);
    uint2 hp, lp;
    hp.x = h[0] | ((unsigned)h[1] << 16); hp.y = h[2] | ((unsigned)h[3] << 16);
    lp.x = l[0] | ((unsigned)l[1] << 16); lp.y = l[2] | ((unsigned)l[3] << 16);
    *(uint2*)(dst)       = hp;
    *(uint2*)(dst + 512) = lp;
}

// ---------------------------------------------------------------------------
__global__ __launch_bounds__(256) void build_pad_split(
    const float* __restrict__ src0, const float* __restrict__ src1,
    const float* __restrict__ front, const float* __restrict__ back,
    unsigned short* __restrict__ d0, unsigned short* __restrict__ d1)
{
    const float* x = blockIdx.z ? src1 : src0;
    unsigned short* xp2 = blockIdx.z ? d1 : d0;
    int idx = blockIdx.x * 256 + threadIdx.x;   // over B*PAD*128
    int c4 = idx & 127;
    int rest = idx >> 7;
    int p = rest % PAD;
    int b = rest / PAD;
    float4 val;
    if (p < WIDTH) {
        val = *(const float4*)(front + (size_t)p * HID + c4 * 4);
    } else if (p < WIDTH + S) {
        val = *(const float4*)(x + ((size_t)b * S + (p - WIDTH)) * HID + c4 * 4);
    } else {
        val = *(const float4*)(back + (size_t)(p - WIDTH - S) * HID + c4 * 4);
    }
    store_split4(xp2 + (size_t)(b * PAD + p) * RS + c4 * 4, val);
}

// ---------------------------------------------------------------------------
// per-use weight conversion (fallback paths): fp32 [R,HID] -> split [R,RS]
// ---------------------------------------------------------------------------
__global__ __launch_bounds__(256) void conv_w(
    const float* __restrict__ s0, const float* __restrict__ s1,
    unsigned short* __restrict__ w0, unsigned short* __restrict__ w1)
{
    const float* src = blockIdx.z ? s1 : s0;
    unsigned short* dst = blockIdx.z ? w1 : w0;
    int idx = blockIdx.x * 256 + threadIdx.x;
    int c4 = idx & 127;
    int r  = idx >> 7;
    float4 v = *(const float4*)(src + (size_t)r * HID + c4 * 4);
    store_split4(dst + (size_t)r * RS + c4 * 4, v);
}

// ---------------------------------------------------------------------------
// one-shot conversion of ALL weights -> w2all [2 dirs][8192 rows][RS].
// per (dir,layer): rows 0..2047 = lin_w (q,k,v,out), 2048..4095 = hw_w with
// PERMUTED rows: orig (i_hw, rr2): c=rr2&511, is_g=rr2>>9 ->
// p = 32*(c>>4) + (c&15) + 16*is_g  (16-col nl/gate interleave so the fused
// hw epilogue holds nl and gate for the same col in the same lane).
// ---------------------------------------------------------------------------
__global__ __launch_bounds__(256) void conv_all(
    const float* __restrict__ fw_lin_w, const float* __restrict__ bw_lin_w,
    const float* __restrict__ fw_hw_w,  const float* __restrict__ bw_hw_w,
    unsigned short* __restrict__ w2all)
{
    int idx = blockIdx.x * 256 + threadIdx.x;   // over 8192*128
    int c4 = idx & 127;
    int r  = idx >> 7;          // 0..8191
    int l  = r >> 12;           // layer
    int rr = r & 4095;
    const float* lin = blockIdx.z ? bw_lin_w : fw_lin_w;
    const float* hw  = blockIdx.z ? bw_hw_w  : fw_hw_w;
    const float* src;
    size_t drow;
    if (rr < 2048) {
        src  = lin + ((size_t)l * 2048 + rr) * HID;
        drow = (size_t)blockIdx.z * 8192 + (size_t)l * 4096 + rr;
    } else {
        int sub  = rr - 2048;
        int i_hw = sub >> 10;
        int rr2  = sub & 1023;
        int c    = rr2 & 511;
        int is_g = rr2 >> 9;
        int p    = ((c >> 4) << 5) + (c & 15) + (is_g << 4);
        src  = hw + ((size_t)l * 2048 + sub) * HID;
        drow = (size_t)blockIdx.z * 8192 + (size_t)l * 4096 + 2048 + (i_hw << 10) + p;
    }
    float4 v = *(const float4*)(src + c4 * 4);
    store_split4(w2all + drow * RS + c4 * 4, v);
}

// ---------------------------------------------------------------------------
// Split-bf16 MFMA GEMM (NT), single-buffered, K2=1024.
// A segs [H,L]: aoff=k0;  B segs [H,H]: boff = k0<512 ? k0 : k0-512.
// Staging: R7 permuted-slot swizzle (coalesced fill + conflict-free reads).
// ---------------------------------------------------------------------------
__global__ __launch_bounds__(256) void gemm_split(
    const unsigned short* __restrict__ A0, const unsigned short* __restrict__ B0,
    const float* __restrict__ bias0, float* __restrict__ C0,
    const unsigned short* __restrict__ A1, const unsigned short* __restrict__ B1,
    const float* __restrict__ bias1, float* __restrict__ C1,
    int N)
{
    const unsigned short* A  = blockIdx.z ? A1 : A0;
    const unsigned short* Bw = blockIdx.z ? B1 : B0;
    const float* bias        = blockIdx.z ? bias1 : bias0;
    float* C                 = blockIdx.z ? C1 : C0;

    __shared__ unsigned short Als[128 * 32];
    __shared__ unsigned short Bls[128 * 32];

    const int tid  = threadIdx.x;
    const int wave = tid >> 6;
    const int lane = tid & 63;
    const int bm = blockIdx.y * 128;
    const int bn = blockIdx.x * 128;
    const int wm = (wave >> 1) * 64;
    const int wn = (wave & 1) * 64;

    const int c0 = wave * 2, c1 = wave * 2 + 1;
    const int lr = lane >> 2;
    const int kg = ((lane & 3) + (lr >> 1)) & 3;
    const int sr0 = c0 * 16 + lr;
    const int sr1 = c1 * 16 + lr;
    const int sc  = kg * 8;
    const unsigned short* Ag0 = A  + (size_t)(bm + sr0) * RS + sc;
    const unsigned short* Ag1 = A  + (size_t)(bm + sr1) * RS + sc;
    const unsigned short* Bg0 = Bw + (size_t)(bn + sr0) * RS + sc;
    const unsigned short* Bg1 = Bw + (size_t)(bn + sr1) * RS + sc;
    const int ls0 = c0 * 512;
    const int ls1 = c1 * 512;

    const int fr = lane & 15;
    const int q  = lane >> 4;
    const int rslot = (4 * fr + ((q - (fr >> 1)) & 3)) * 8;

    f4 acc[4][4] = {};

    for (int k0 = 0; k0 < K2; k0 += 32) {
        const int aoff = k0;
        const int boff = (k0 < 512) ? k0 : (k0 - 512);
        __builtin_amdgcn_global_load_lds(
            (const __attribute__((address_space(1))) void*)(Ag0 + aoff),
            (__attribute__((address_space(3))) void*)&Als[ls0], 16, 0, 0);
        __builtin_amdgcn_global_load_lds(
            (const __attribute__((address_space(1))) void*)(Ag1 + aoff),
            (__attribute__((address_space(3))) void*)&Als[ls1], 16, 0, 0);
        __builtin_amdgcn_global_load_lds(
            (const __attribute__((address_space(1))) void*)(Bg0 + boff),
            (__attribute__((address_space(3))) void*)&Bls[ls0], 16, 0, 0);
        __builtin_amdgcn_global_load_lds(
            (const __attribute__((address_space(1))) void*)(Bg1 + boff),
            (__attribute__((address_space(3))) void*)&Bls[ls1], 16, 0, 0);
        __syncthreads();

        s8 a[4], b[4];
        #pragma unroll
        for (int i = 0; i < 4; ++i)
            a[i] = *(const s8*)&Als[((wm >> 4) + i) * 512 + rslot];
        #pragma unroll
        for (int j = 0; j < 4; ++j)
            b[j] = *(const s8*)&Bls[((wn >> 4) + j) * 512 + rslot];
        #pragma unroll
        for (int i = 0; i < 4; ++i)
            #pragma unroll
            for (int j = 0; j < 4; ++j)
                acc[i][j] = __builtin_amdgcn_mfma_f32_16x16x32_bf16(
                    a[i], b[j], acc[i][j], 0, 0, 0);
        __syncthreads();
    }

    const int col = lane & 15;
    const int rb  = (lane >> 4) * 4;
    #pragma unroll
    for (int j = 0; j < 4; ++j) {
        float bj = bias[bn + wn + j * 16 + col];
        #pragma unroll
        for (int i = 0; i < 4; ++i) {
            size_t base = (size_t)(bm + wm + i * 16 + rb) * N + (bn + wn + j * 16 + col);
            #pragma unroll
            for (int r = 0; r < 4; ++r)
                C[base + (size_t)r * N] = acc[i][j][r] + bj;
        }
    }
}

// ---------------------------------------------------------------------------
// Fused highway GEMM (wall path): N=1024 permuted weights (nl/gate 16-col
// interleave). Epilogue applies the gate: x is read from A itself (h+l),
// nl = frag 2p, gate = frag 2p+1 (same lane, same orig col).
// first=1: writes split acts -> o2 (ping buffer, NOT A: other blocks still
// read A). first=0: writes fp32 dst + output slice.
// ---------------------------------------------------------------------------
__global__ __launch_bounds__(256) void gemm_hw_fused(
    const unsigned short* __restrict__ A0, const unsigned short* __restrict__ B0,
    const float* __restrict__ hwb0, unsigned short* __restrict__ o2_0,
    float* __restrict__ dst0, float* __restrict__ osl0,
    const unsigned short* __restrict__ A1, const unsigned short* __restrict__ B1,
    const float* __restrict__ hwb1, unsigned short* __restrict__ o2_1,
    float* __restrict__ dst1, float* __restrict__ osl1,
    int first)
{
    const unsigned short* A  = blockIdx.z ? A1 : A0;
    const unsigned short* Bw = blockIdx.z ? B1 : B0;
    const float* hwb         = blockIdx.z ? hwb1 : hwb0;
    unsigned short* o2       = blockIdx.z ? o2_1 : o2_0;
    float* dstf              = blockIdx.z ? dst1 : dst0;
    float* osl               = blockIdx.z ? osl1 : osl0;

    __shared__ unsigned short Als[128 * 32];
    __shared__ unsigned short Bls[128 * 32];

    const int tid  = threadIdx.x;
    const int wave = tid >> 6;
    const int lane = tid & 63;
    const int bm = blockIdx.y * 128;
    const int bn = blockIdx.x * 128;
    const int wm = (wave >> 1) * 64;
    const int wn = (wave & 1) * 64;

    const int c0 = wave * 2, c1 = wave * 2 + 1;
    const int lr = lane >> 2;
    const int kg = ((lane & 3) + (lr >> 1)) & 3;
    const int sr0 = c0 * 16 + lr;
    const int sr1 = c1 * 16 + lr;
    const int sc  = kg * 8;
    const unsigned short* Ag0 = A  + (size_t)(bm + sr0) * RS + sc;
    const unsigned short* Ag1 = A  + (size_t)(bm + sr1) * RS + sc;
    const unsigned short* Bg0 = Bw + (size_t)(bn + sr0) * RS + sc;
    const unsigned short* Bg1 = Bw + (size_t)(bn + sr1) * RS + sc;
    const int ls0 = c0 * 512;
    const int ls1 = c1 * 512;

    const int fr = lane & 15;
    const int q  = lane >> 4;
    const int rslot = (4 * fr + ((q - (fr >> 1)) & 3)) * 8;

    f4 acc[4][4] = {};

    for (int k0 = 0; k0 < K2; k0 += 32) {
        const int aoff = k0;
        const int boff = (k0 < 512) ? k0 : (k0 - 512);
        __builtin_amdgcn_global_load_lds(
            (const __attribute__((address_space(1))) void*)(Ag0 + aoff),
            (__attribute__((address_space(3))) void*)&Als[ls0], 16, 0, 0);
        __builtin_amdgcn_global_load_lds(
            (const __attribute__((address_space(1))) void*)(Ag1 + aoff),
            (__attribute__((address_space(3))) void*)&Als[ls1], 16, 0, 0);
        __builtin_amdgcn_global_load_lds(
            (const __attribute__((address_space(1))) void*)(Bg0 + boff),
            (__attribute__((address_space(3))) void*)&Bls[ls0], 16, 0, 0);
        __builtin_amdgcn_global_load_lds(
            (const __attribute__((address_space(1))) void*)(Bg1 + boff),
            (__attribute__((address_space(3))) void*)&Bls[ls1], 16, 0, 0);
        __syncthreads();

        s8 a[4], b[4];
        #pragma unroll
        for (int i = 0; i < 4; ++i)
            a[i] = *(const s8*)&Als[((wm >> 4) + i) * 512 + rslot];
        #pragma unroll
        for (int j = 0; j < 4; ++j)
            b[j] = *(const s8*)&Bls[((wn >> 4) + j) * 512 + rslot];
        #pragma unroll
        for (int i = 0; i < 4; ++i)
            #pragma unroll
            for (int j = 0; j < 4; ++j)
                acc[i][j] = __builtin_amdgcn_mfma_f32_16x16x32_bf16(
                    a[i], b[j], acc[i][j], 0, 0, 0);
        __syncthreads();
    }

    const int col = lane & 15;
    const int rb  = (lane >> 4) * 4;
    #pragma unroll
    for (int jp = 0; jp < 2; ++jp) {
        const int cc = ((bn + wn) >> 1) + jp * 16 + col;   // orig col 0..511
        const float bnl = hwb[cc];
        const float bg  = hwb[512 + cc];
        #pragma unroll
        for (int i = 0; i < 4; ++i) {
            #pragma unroll
            for (int r = 0; r < 4; ++r) {
                const int row = bm + wm + i * 16 + rb + r;
                float nl = acc[i][2 * jp][r] + bnl;
                float g  = acc[i][2 * jp + 1][r] + bg;
                float xv = bf2f(A[(size_t)row * RS + cc])
                         + bf2f(A[(size_t)row * RS + cc + 512]);
                float sg = 1.f / (1.f + __expf(-g));
                float o  = sg * xv + (1.f - sg) * fmaxf(nl, 0.f);
                if (first) {
                    unsigned short hh, ll; split2(o, hh, ll);
                    o2[(size_t)row * RS + cc]       = hh;
                    o2[(size_t)row * RS + cc + 512] = ll;
                } else {
                    dstf[(size_t)row * HID + cc]      = o;
                    osl[(size_t)row * (2 * HID) + cc] = o;
                }
            }
        }
    }
}

// ---------------------------------------------------------------------------
// Banded MHA. One wave per (b,h,i). backward = dir0 + z.
// ---------------------------------------------------------------------------
__global__ __launch_bounds__(256) void banded_attn(
    const float* __restrict__ Q0, const float* __restrict__ Q1,
    unsigned short* __restrict__ O0, unsigned short* __restrict__ O1,
    int dir0)
{
    const float* QKV = blockIdx.z ? Q1 : Q0;
    unsigned short* O2 = blockIdx.z ? O1 : O0;
    int backward = dir0 + blockIdx.z;

    int w    = blockIdx.x * 4 + (threadIdx.x >> 6);
    int lane = threadIdx.x & 63;
    int i  = w % PAD;
    int bh = w / PAD;
    int h  = bh & (NHEADS - 1);
    int b  = bh / NHEADS;

    int jlo, n;
    if (backward) { jlo = i; n = min(WIDTH + 2, PAD - i); }
    else          { jlo = max(0, i - WIDTH - 1); n = i - jlo + 1; }

    const int s = lane >> 4;
    const int d = lane & 15;
    const size_t rowbase = (size_t)(b * PAD) * 1536;
    const int colq = h * DK;

    float4 q4 = *(const float4*)(QKV + rowbase + (size_t)i * 1536 + colq + 4 * d);

    float sc[5];
    #pragma unroll
    for (int m = 0; m < 5; ++m) {
        int t  = 4 * m + s;
        int tc = t < n ? t : n - 1;
        float4 kv = *(const float4*)(QKV + rowbase + (size_t)(jlo + tc) * 1536
                                     + 512 + colq + 4 * d);
        float p = q4.x * kv.x + q4.y * kv.y + q4.z * kv.z + q4.w * kv.w;
        p += __shfl_xor(p, 1);
        p += __shfl_xor(p, 2);
        p += __shfl_xor(p, 4);
        p += __shfl_xor(p, 8);
        sc[m] = p * 0.125f;
    }

    float sv[WIDTH + 2];
    #pragma unroll
    for (int t = 0; t < WIDTH + 2; ++t) {
        float v = __shfl(sc[t >> 2], (t & 3) << 4);
        sv[t] = (t < n) ? v : -1e30f;
    }
    float mx = sv[0];
    #pragma unroll
    for (int t = 1; t < WIDTH + 2; ++t) mx = fmaxf(mx, sv[t]);
    float denom = 0.f;
    #pragma unroll
    for (int t = 0; t < WIDTH + 2; ++t) { sv[t] = __expf(sv[t] - mx); denom += sv[t]; }
    float inv = 1.0f / denom;

    float od0 = 0.f, od1 = 0.f;
    #pragma unroll
    for (int t = 0; t < WIDTH + 2; t += 2) {
        int tc0 = t     < n ? t     : n - 1;
        int tc1 = t + 1 < n ? t + 1 : n - 1;
        od0 += sv[t]     * QKV[rowbase + (size_t)(jlo + tc0) * 1536 + 1024 + colq + lane];
        od1 += sv[t + 1] * QKV[rowbase + (size_t)(jlo + tc1) * 1536 + 1024 + colq + lane];
    }
    float od = (od0 + od1) * inv;

    unsigned short hh, ll;
    split2(od, hh, ll);
    size_t ro = (size_t)(b * PAD + i) * RS + colq + lane;
    O2[ro] = hh; O2[ro + 512] = ll;
}

// ---------------------------------------------------------------------------
__global__ __launch_bounds__(256) void rel_combine(
    const float* __restrict__ a0, const float* __restrict__ a1,
    const float* __restrict__ w0, const float* __restrict__ w1,
    unsigned short* __restrict__ f0, unsigned short* __restrict__ f1,
    int off0, int off1)
{
    const float* att = blockIdx.z ? a1 : a0;
    const float* w   = blockIdx.z ? w1 : w0;
    unsigned short* fo2 = blockIdx.z ? f1 : f0;
    int offset = blockIdx.z ? off1 : off0;

    int idx = blockIdx.x * 256 + threadIdx.x;   // over B*S*128
    int c4 = idx & 127;
    int rest = idx >> 7;
    int t = rest & (S - 1);
    int b = rest >> 10;

    const float* rowbase = att + (size_t)b * PAD * HID + c4 * 4;
    float4 acc = *(const float4*)(rowbase + (size_t)(WIDTH + t) * HID);
    #pragma unroll
    for (int k = 0; k <= WIDTH; ++k) {
        float wk = w[k];
        float4 xv = *(const float4*)(rowbase + (size_t)(offset + k + t) * HID);
        acc.x += wk * xv.x; acc.y += wk * xv.y;
        acc.z += wk * xv.z; acc.w += wk * xv.w;
    }
    store_split4(fo2 + ((size_t)b * S + t) * RS + c4 * 4, acc);
}

// ---------------------------------------------------------------------------
// standalone highway gate (non-wall fallback only)
// ---------------------------------------------------------------------------
__global__ __launch_bounds__(256) void highway_gate(
    const unsigned short* __restrict__ x0, const unsigned short* __restrict__ x1,
    const float* __restrict__ p0, const float* __restrict__ p1,
    float* __restrict__ of0, float* __restrict__ of1,
    unsigned short* __restrict__ o20, unsigned short* __restrict__ o21,
    float* __restrict__ os0, float* __restrict__ os1)
{
    const unsigned short* x2 = blockIdx.z ? x1 : x0;
    const float* proj        = blockIdx.z ? p1 : p0;
    float* outf              = blockIdx.z ? of1 : of0;
    unsigned short* out2     = blockIdx.z ? o21 : o20;
    float* oslice            = blockIdx.z ? os1 : os0;

    int idx = blockIdx.x * 256 + threadIdx.x;   // over B*S*128
    int c4 = idx & 127;
    int r  = idx >> 7;
    const unsigned short* xr = x2 + (size_t)r * RS + c4 * 4;
    uint2 hp = *(const uint2*)(xr);
    uint2 lp = *(const uint2*)(xr + 512);
    float4 xv;
    xv.x = bf2f((unsigned short)(hp.x & 0xffff)) + bf2f((unsigned short)(lp.x & 0xffff));
    xv.y = bf2f((unsigned short)(hp.x >> 16))    + bf2f((unsigned short)(lp.x >> 16));
    xv.z = bf2f((unsigned short)(hp.y & 0xffff)) + bf2f((unsigned short)(lp.y & 0xffff));
    xv.w = bf2f((unsigned short)(hp.y >> 16))    + bf2f((unsigned short)(lp.y >> 16));

    float4 nl = *(const float4*)(proj + (size_t)r * (2 * HID) + c4 * 4);
    float4 g  = *(const float4*)(proj + (size_t)r * (2 * HID) + HID + c4 * 4);
    float4 o;
    float sg;
    sg = 1.f / (1.f + __expf(-g.x)); o.x = sg * xv.x + (1.f - sg) * fmaxf(nl.x, 0.f);
    sg = 1.f / (1.f + __expf(-g.y)); o.y = sg * xv.y + (1.f - sg) * fmaxf(nl.y, 0.f);
    sg = 1.f / (1.f + __expf(-g.z)); o.z = sg * xv.z + (1.f - sg) * fmaxf(nl.z, 0.f);
    sg = 1.f / (1.f + __expf(-g.w)); o.w = sg * xv.w + (1.f - sg) * fmaxf(nl.w, 0.f);
    if (outf)   *(float4*)(outf + (size_t)idx * 4) = o;
    if (out2)   store_split4(out2 + (size_t)r * RS + c4 * 4, o);
    if (oslice) *(float4*)(oslice + (size_t)r * (2 * HID) + c4 * 4) = o;
}

// ---------------------------------------------------------------------------
extern "C" void kernel_launch(void* const* d_in, const int* in_sizes, int n_in,
                              void* d_out, int out_size, void* d_ws, size_t ws_size,
                              hipStream_t stream)
{
    const float* inputs   = (const float*)d_in[0];
    const float* fw_lin_w = (const float*)d_in[2];
    const float* fw_lin_b = (const float*)d_in[3];
    const float* bw_lin_w = (const float*)d_in[4];
    const float* bw_lin_b = (const float*)d_in[5];
    const float* fw_hw_w  = (const float*)d_in[6];
    const float* fw_hw_b  = (const float*)d_in[7];
    const float* bw_hw_w  = (const float*)d_in[8];
    const float* bw_hw_b  = (const float*)d_in[9];
    const float* fw_pad   = (const float*)d_in[10];
    const float* bw_pad   = (const float*)d_in[11];
    const float* fw_rel   = (const float*)d_in[12];
    const float* bw_rel   = (const float*)d_in[13];
    float* out = (float*)d_out;
    float* ws  = (float*)d_ws;

    const size_t BSH  = (size_t)B * S * HID;      // 2,097,152 floats
    const size_t QKVF = (size_t)B * PAD * 1536;   // 6,488,064 floats per dir
    const int MP = B * PAD;                       // 4224
    const int MS = B * S;                         // 4096

    const size_t GROUPED_FLOATS = 2 * QKVF + (2 * (size_t)MP * RS + 2 * (size_t)1536 * RS) / 2;
    const size_t WALL_FLOATS    = 2 * QKVF + (2 * (size_t)MP * RS + (size_t)2 * 8192 * RS) / 2;
    const bool wall    = ws_size >= WALL_FLOATS * 4;
    const bool grouped = wall || ws_size >= GROUPED_FLOATS * 4;
    const int G = grouped ? 2 : 1;

    float* f  = ws;
    float* bk = f + BSH;

    float* QKV[2]; float* ATT[2]; float* HWP[2];
    unsigned short* ACT2[2]; unsigned short* W2[2];
    unsigned short* ACT2B[2] = {nullptr, nullptr};
    unsigned short* w2all = nullptr;
    if (grouped) {
        QKV[0] = ws;             QKV[1] = ws + QKVF;
        float* extra = ws + 2 * BSH;
        ATT[0] = extra;          ATT[1] = extra + (size_t)MP * HID;
        HWP[0] = extra;          HWP[1] = extra + (size_t)MS * 1024;
        // ping buffer for fused hw (aliases ATT/HWP region; dead by hw phase)
        ACT2B[0] = (unsigned short*)extra;
        ACT2B[1] = ACT2B[0] + (size_t)MS * RS;
        unsigned short* a2 = (unsigned short*)(ws + 2 * QKVF);
        ACT2[0] = a2;            ACT2[1] = a2 + (size_t)MP * RS;
        unsigned short* w2 = a2 + 2 * (size_t)MP * RS;
        if (wall) { w2all = w2; W2[0] = W2[1] = nullptr; }
        else      { W2[0] = w2; W2[1] = w2 + (size_t)1536 * RS; }
    } else {
        float* qkvS = bk + BSH;
        QKV[0] = QKV[1] = qkvS;
        ATT[0] = ATT[1] = qkvS;
        HWP[0] = HWP[1] = qkvS;
        unsigned short* a2 = (unsigned short*)(qkvS + QKVF);
        ACT2[0] = ACT2[1] = a2;
        W2[0] = W2[1] = a2 + (size_t)MP * RS;
    }

    if (wall) {
        conv_all<<<dim3(8192 * 128 / 256, 1, 2), 256, 0, stream>>>(
            fw_lin_w, bw_lin_w, fw_hw_w, bw_hw_w, w2all);
    }
    // w2all row offsets per (dir,l): QKV=0, out=1536, hw_i=2048+1024*i
    auto WB = [&](int dir, int l, int seg) -> unsigned short* {
        return w2all + ((size_t)dir * 8192 + (size_t)l * 4096 + seg) * RS;
    };

    for (int l = 0; l < NLAYERS; ++l) {
        const float* LINW[2] = {fw_lin_w + (size_t)l * 4 * HID * HID,
                                bw_lin_w + (size_t)l * 4 * HID * HID};
        const float* LINB[2] = {fw_lin_b + (size_t)l * 4 * HID,
                                bw_lin_b + (size_t)l * 4 * HID};
        const float* HWW[2]  = {fw_hw_w + (size_t)l * NHW * 2 * HID * HID,
                                bw_hw_w + (size_t)l * NHW * 2 * HID * HID};
        const float* HWB[2]  = {fw_hw_b + (size_t)l * NHW * 2 * HID,
                                bw_hw_b + (size_t)l * NHW * 2 * HID};
        const float* RELW[2] = {fw_rel + (size_t)l * (WIDTH + 1),
                                bw_rel + (size_t)l * (WIDTH + 1)};
        const float* front = fw_pad + (size_t)l * WIDTH * HID;
        const float* back  = bw_pad + (size_t)l * WIDTH * HID;
        float* DST[2] = {f, bk};
        float* OSL[2] = {out + (size_t)l * B * S * 2 * HID,
                         out + (size_t)l * B * S * 2 * HID + HID};
        const float* SRC[2] = {(l == 0) ? inputs : f, (l == 0) ? inputs : bk};

        for (int d0 = 0; d0 < 2; d0 += G) {
            const int dB = (G == 2) ? 1 : d0;

            build_pad_split<<<dim3(MP * 128 / 256, 1, G), 256, 0, stream>>>(
                SRC[d0], SRC[dB], front, back, ACT2[0], ACT2[1]);

            unsigned short *wq0, *wq1;
            if (wall) { wq0 = WB(d0, l, 0); wq1 = WB(dB, l, 0); }
            else {
                conv_w<<<dim3(1536 * 128 / 256, 1, G), 256, 0, stream>>>(
                    LINW[d0], LINW[dB], W2[0], W2[1]);
                wq0 = W2[0]; wq1 = W2[1];
            }
            gemm_split<<<dim3(1536 / 128, MP / 128, G), 256, 0, stream>>>(
                ACT2[0], wq0, LINB[d0], QKV[0],
                ACT2[1], wq1, LINB[dB], QKV[1], 1536);

            banded_attn<<<dim3(B * NHEADS * PAD / 4, 1, G), 256, 0, stream>>>(
                QKV[0], QKV[1], ACT2[0], ACT2[1], d0);

            unsigned short *wo0, *wo1;
            if (wall) { wo0 = WB(d0, l, 1536); wo1 = WB(dB, l, 1536); }
            else {
                conv_w<<<dim3(512 * 128 / 256, 1, G), 256, 0, stream>>>(
                    LINW[d0] + 3 * (size_t)HID * HID, LINW[dB] + 3 * (size_t)HID * HID,
                    W2[0], W2[1]);
                wo0 = W2[0]; wo1 = W2[1];
            }
            gemm_split<<<dim3(512 / 128, MP / 128, G), 256, 0, stream>>>(
                ACT2[0], wo0, LINB[d0] + 3 * HID, ATT[0],
                ACT2[1], wo1, LINB[dB] + 3 * HID, ATT[1], 512);

            rel_combine<<<dim3(MS * 128 / 256, 1, G), 256, 0, stream>>>(
                ATT[0], ATT[1], RELW[d0], RELW[dB], ACT2[0], ACT2[1],
                d0 * WIDTH, dB * WIDTH);

            if (wall) {
                // hw0: act2 -> act2b (ping), gate fused
                gemm_hw_fused<<<dim3(1024 / 128, MS / 128, G), 256, 0, stream>>>(
                    ACT2[0], WB(d0, l, 2048), HWB[d0], ACT2B[0], nullptr, nullptr,
                    ACT2[1], WB(dB, l, 2048), HWB[dB], ACT2B[1], nullptr, nullptr, 1);
                // hw1: act2b -> dst + output slice, gate fused
                gemm_hw_fused<<<dim3(1024 / 128, MS / 128, G), 256, 0, stream>>>(
                    ACT2B[0], WB(d0, l, 3072), HWB[d0] + 1024, nullptr, DST[d0], OSL[d0],
                    ACT2B[1], WB(dB, l, 3072), HWB[dB] + 1024, nullptr, DST[dB], OSL[dB], 0);
            } else {
                for (int i = 0; i < NHW; ++i) {
                    conv_w<<<dim3(1024 * 128 / 256, 1, G), 256, 0, stream>>>(
                        HWW[d0] + (size_t)i * 2 * HID * HID,
                        HWW[dB] + (size_t)i * 2 * HID * HID, W2[0], W2[1]);
                    gemm_split<<<dim3(1024 / 128, MS / 128, G), 256, 0, stream>>>(
                        ACT2[0], W2[0], HWB[d0] + (size_t)i * 2 * HID, HWP[0],
                        ACT2[1], W2[1], HWB[dB] + (size_t)i * 2 * HID, HWP[1], 1024);
                    const bool last = (i == NHW - 1);
                    highway_gate<<<dim3(MS * 128 / 256, 1, G), 256, 0, stream>>>(
                        ACT2[0], ACT2[1], HWP[0], HWP[1],
                        last ? DST[d0] : (float*)nullptr,
                        last ? DST[dB] : (float*)nullptr,
                        last ? (unsigned short*)nullptr : ACT2[0],
                        last ? (unsigned short*)nullptr : ACT2[1],
                        last ? OSL[d0] : (float*)nullptr,
                        last ? OSL[dB] : (float*)nullptr);
                }
            }
        }
    }
}